// Round 11
// baseline (461.752 us; speedup 1.0000x reference)
//
#include <hip/hip_runtime.h>
#include <hip/hip_bf16.h>
#include <hip/hip_fp16.h>
#include <stdint.h>

typedef _Float16 f16;
typedef _Float16 f16x4 __attribute__((ext_vector_type(4)));
typedef _Float16 f16x8 __attribute__((ext_vector_type(8)));
typedef float f32x4 __attribute__((ext_vector_type(4)));

#define NB 8192
#define ND 1024
#define NU 1024
#define NE 16

// ---------------- merged prep: W transpose-cast + X cast, one launch ----------------
__global__ __launch_bounds__(256) void k_prep(const float* __restrict__ W,
                                              f16* __restrict__ WT,
                                              const float* __restrict__ X,
                                              f16* __restrict__ Xh) {
  const int bid = blockIdx.x;
  const int t = threadIdx.x;
  if (bid < 4096) {
    __shared__ f16 tile[64][68];
    const int u0 = (bid & 15) * 64;
    const int d0 = ((bid >> 4) & 15) * 64;
    const int e = bid >> 8;
    const int r = t >> 4;
    const int c = (t & 15) << 2;
    const float* src = W + (size_t)e * ND * NU;
    f16* dst = WT + (size_t)e * NU * ND;
#pragma unroll
    for (int i = 0; i < 4; ++i) {
      const int rr = r + i * 16;
      const float4 v = *(const float4*)(src + (size_t)(d0 + rr) * NU + (u0 + c));
      tile[rr][c + 0] = (f16)v.x;
      tile[rr][c + 1] = (f16)v.y;
      tile[rr][c + 2] = (f16)v.z;
      tile[rr][c + 3] = (f16)v.w;
    }
    __syncthreads();
#pragma unroll
    for (int i = 0; i < 4; ++i) {
      const int rr = r + i * 16;
      f16x4 h;
      h[0] = tile[c + 0][rr];
      h[1] = tile[c + 1][rr];
      h[2] = tile[c + 2][rr];
      h[3] = tile[c + 3][rr];
      *(f16x4*)(dst + (size_t)(u0 + rr) * ND + (d0 + c)) = h;
    }
  } else {
    const size_t i = ((size_t)(bid - 4096) * 256 + t) * 8;
    const float4 v0 = *(const float4*)(X + i);
    const float4 v1 = *(const float4*)(X + i + 4);
    f16x8 h;
    h[0] = (f16)v0.x; h[1] = (f16)v0.y; h[2] = (f16)v0.z; h[3] = (f16)v0.w;
    h[4] = (f16)v1.x; h[5] = (f16)v1.y; h[6] = (f16)v1.z; h[7] = (f16)v1.w;
    *(f16x8*)(Xh + i) = h;
  }
}

// ================= PHASE A: persistent 256x256 GEMM + exp epilogue =================
// B-DIRECT variant: only A is LDS-staged (2x32KB dbuf); B fragments load straight
// from the block's L2-resident 512KB panel into regs, staggered-reloaded (b01/b23
// refetched for kt+1 right after last use in kt => 32 b-regs, no double buffer).
// One barrier per K-tile: all stages target nxt only (WAR-safe: reads of cur retire
// before each wave's MFMA issue; barrier at K-tile end covers both directions).
// FIFO discipline: sched_barrier(0) pins the 4 A-stage instrs before the 8 b-loads,
// so vmcnt(8) at K-tile end provably retires the stages.

typedef __attribute__((address_space(3))) void lds_void_t;
typedef __attribute__((address_space(1))) const void gbl_void_t;

__device__ __forceinline__ void gload16(const void* g, void* l) {
  __builtin_amdgcn_global_load_lds((gbl_void_t*)g, (lds_void_t*)l, 16, 0, 0);
}

#define WAIT_VM8() do { asm volatile("s_waitcnt vmcnt(8)" ::: "memory"); \
                        __builtin_amdgcn_sched_barrier(0); } while (0)
#define WAIT_LGKM0() do { asm volatile("s_waitcnt lgkmcnt(0)" ::: "memory"); \
                          __builtin_amdgcn_sched_barrier(0); } while (0)
#define BARR() do { asm volatile("" ::: "memory"); __builtin_amdgcn_s_barrier(); \
                    asm volatile("" ::: "memory"); } while (0)

// stage one 16KB half (h) of the A tile for K-tile-local index kl into dbuf buf
#define STAGEA(srcp, h, kl, buf)                                                \
  {                                                                             \
    _Pragma("unroll") for (int i_ = 0; i_ < 2; ++i_) {                          \
      const unsigned s_ = i_ * 512 + t;                                         \
      const unsigned row_ = (h) * 128 + (s_ >> 3);                              \
      const unsigned sch_ = (s_ & 7) ^ (row_ & 7);                              \
      const unsigned lb_ = (unsigned)(buf) * 32768 + (h) * 16384 +              \
                           (i_ * 512 + (t & ~63u)) * 16;                        \
      gload16((srcp) + (size_t)row_ * 2048 + (size_t)(kl) * 128 + sch_ * 16,    \
              smem + lb_);                                                      \
    }                                                                           \
  }

#define LDA(mb0, buf)                                                           \
  _Pragma("unroll") for (int j_ = 0; j_ < 4; ++j_)                              \
    _Pragma("unroll") for (int ks_ = 0; ks_ < 2; ++ks_)                         \
      a[j_][ks_] = *(const f16x8*)(smem + (unsigned)(buf) * 32768 +             \
                     (wr * 128 + ((mb0) + j_) * 16 + ln) * 128 +                \
                     (((unsigned)(ks_ * 4 + g)) ^ (ln & 7u)) * 16);

// load 2 B n-blocks (n0, n0+1) x 2 k-slices straight from global (linear layout)
#define BLOAD2(n0, kl)                                                          \
  _Pragma("unroll") for (int n_ = (n0); n_ < (n0) + 2; ++n_)                    \
    _Pragma("unroll") for (int ks_ = 0; ks_ < 2; ++ks_)                         \
      b[n_][ks_] = *(const f16x8*)(Bg + (size_t)(wc * 64 + n_ * 16 + ln) * 2048 \
                     + (size_t)(kl) * 128 + (unsigned)(ks_ * 4 + g) * 16);

#define QUAD(mb0, n0)                                                           \
  _Pragma("unroll") for (int j_ = 0; j_ < 4; ++j_)                              \
    _Pragma("unroll") for (int n_ = 0; n_ < 2; ++n_)                            \
      _Pragma("unroll") for (int ks_ = 0; ks_ < 2; ++ks_)                       \
        acc[(mb0) + j_][(n0) + n_] = __builtin_amdgcn_mfma_f32_16x16x32_f16(    \
            a[j_][ks_], b[(n0) + n_][ks_], acc[(mb0) + j_][(n0) + n_], 0, 0, 0);

__global__ __launch_bounds__(512, 2) void k_gemm_exp(const f16* __restrict__ Xc,
                                                     const f16* __restrict__ WT,
                                                     const float* __restrict__ BIAS,
                                                     f16* __restrict__ P,
                                                     float* __restrict__ S4,
                                                     int TPB, int CR) {
  __shared__ alignas(16) unsigned char smem[65536 + 4096];  // A dbuf + red
  float* red = (float*)(smem + 65536);

  const int t = threadIdx.x;
  const int w = t >> 6;
  const int l = t & 63;
  const int g = l >> 4;
  const int ln = l & 15;
  const int wr = w >> 2;  // 0..1
  const int wc = w & 3;   // 0..3

  const int bid = blockIdx.x;
  const int xcd = bid & 7;
  const int i = bid >> 3;
  const int ntl = i >> 2;
  const int q = i & 3;
  const int nt = xcd * 8 + ntl;
  const int mt0 = q * TPB;

  const char* Xc0 = (const char*)Xc;
  const char* Bg = (const char*)WT + (size_t)nt * 256 * 2048;

  f32x4 acc[8][4];
#pragma unroll
  for (int mb = 0; mb < 8; ++mb)
#pragma unroll
    for (int nb = 0; nb < 4; ++nb) acc[mb][nb] = (f32x4){0.f, 0.f, 0.f, 0.f};

  f16x8 a[4][2], b[4][2];

  float bv[4];
  const float* bp = BIAS + ((size_t)(nt >> 2) << 10) + (nt & 3) * 256 + wc * 64 + ln;
#pragma unroll
  for (int nb = 0; nb < 4; ++nb) bv[nb] = bp[nb * 16];

  const int TOT = TPB * 16;

  // prologue: stage A(kt=0) into buf0 (first in FIFO), then b(kt=0)
  {
    const char* Ag0 = Xc0 + (size_t)mt0 * 256 * 2048;
    STAGEA(Ag0, 0, 0, 0);
    STAGEA(Ag0, 1, 0, 0);
    __builtin_amdgcn_sched_barrier(0);  // pin stages before b-loads in the VMEM FIFO
    BLOAD2(0, 0);
    BLOAD2(2, 0);
    WAIT_VM8();  // <=8 outstanding (the 8 b-loads) => A(0) stages retired
    BARR();
  }

#pragma unroll 1
  for (int kt = 0; kt < TOT; ++kt) {
    const int cur = kt & 1, nxt = cur ^ 1;
    const int ti = kt >> 4;
    const bool lastk = (kt == TOT - 1);
    const int kt1 = lastk ? kt : kt + 1;
    const int t1 = kt1 >> 4, kl1 = kt1 & 15;
    const char* Ag1 = Xc0 + (size_t)(mt0 + t1) * 256 * 2048;

    LDA(0, cur);
    if (!lastk) {
      STAGEA(Ag1, 0, kl1, nxt);
      STAGEA(Ag1, 1, kl1, nxt);
    }
    __builtin_amdgcn_sched_barrier(0);  // stages first in FIFO for this K-tile
    __builtin_amdgcn_s_setprio(1);
    QUAD(0, 0);
    QUAD(0, 2);
    __builtin_amdgcn_s_setprio(0);
    LDA(4, cur);
    __builtin_amdgcn_s_setprio(1);
    QUAD(4, 0);
    __builtin_amdgcn_s_setprio(0);
    if (!lastk) BLOAD2(0, kl1);  // b01 free after QUAD(4,0)
    __builtin_amdgcn_s_setprio(1);
    QUAD(4, 2);
    __builtin_amdgcn_s_setprio(0);
    if (!lastk) {
      BLOAD2(2, kl1);            // b23 free after QUAD(4,2)
      WAIT_VM8();                // last 8 = b-loads => A(kt+1) stages retired
    }
    BARR();

    if ((kt & 15) == 15) {
      // ---- epilogue tile ti: bias + exp + P store + row-sums (raw barriers,
      // next-tile stages/b-loads stay in flight) ----
      const int mt = mt0 + ti;
      f16* Prow =
          P + (size_t)(mt * 256 + wr * 128) * 16384 + (size_t)nt * 256 + wc * 64 + ln;
#pragma unroll
      for (int mb = 0; mb < 8; ++mb) {
        float rs[4] = {0.f, 0.f, 0.f, 0.f};
#pragma unroll
        for (int nb = 0; nb < 4; ++nb) {
#pragma unroll
          for (int r = 0; r < 4; ++r) {
            const float p = __expf(acc[mb][nb][r] + bv[nb]);
            rs[r] += p;
            Prow[(size_t)(mb * 16 + g * 4 + r) * 16384 + nb * 16] = (f16)p;
            acc[mb][nb][r] = 0.f;
          }
        }
#pragma unroll
        for (int r = 0; r < 4; ++r) {
          float v = rs[r];
          v += __shfl_xor(v, 1);
          v += __shfl_xor(v, 2);
          v += __shfl_xor(v, 4);
          v += __shfl_xor(v, 8);
          if (ln == 0) red[(wr * 128 + mb * 16 + g * 4 + r) * 4 + wc] = v;
        }
      }
      WAIT_LGKM0();  // red ds_writes visible before raw barrier
      BARR();
      if (t < 256) {
        const float s =
            (red[t * 4 + 0] + red[t * 4 + 1]) + (red[t * 4 + 2] + red[t * 4 + 3]);
        S4[(size_t)nt * CR + mt * 256 + t] = s;
      }
      BARR();
    }
  }
}

// ================= PHASE B: out[b,u] = sum_e (tp/S) * P[b_local,e,u] =================
__global__ __launch_bounds__(512) void k_combine(const f16* __restrict__ P,
                                                 const float* __restrict__ TP,
                                                 const float* __restrict__ S4,
                                                 float* __restrict__ OUT,
                                                 int RB, int CR) {
  __shared__ float c_s[4][16];
  const int t = threadIdx.x;
  const int blk = blockIdx.x;
  if (t < 64) {
    const int rr = t >> 4, e = t & 15;
    const int bl = blk * 4 + rr;
    float S = 0.f;
#pragma unroll
    for (int q = 0; q < 4; ++q) S += S4[(size_t)(e * 4 + q) * CR + bl];
    c_s[rr][e] = TP[(size_t)(RB + bl) * NE + e] / S;
  }
  __syncthreads();
  const int rl = t >> 7;
  const int bl = blk * 4 + rl;
  const int u0 = (t & 127) * 8;
  float acm[8] = {0.f, 0.f, 0.f, 0.f, 0.f, 0.f, 0.f, 0.f};
  const f16* Pb = P + (size_t)bl * 16384 + u0;
#pragma unroll
  for (int e = 0; e < NE; ++e) {
    const float c = c_s[rl][e];
    const f16x8 pv = *(const f16x8*)(Pb + e * 1024);
#pragma unroll
    for (int jj = 0; jj < 8; ++jj) acm[jj] += c * (float)pv[jj];
  }
  float* op = OUT + (size_t)(RB + bl) * NU + u0;
  *(float4*)(op) = (float4){acm[0], acm[1], acm[2], acm[3]};
  *(float4*)(op + 4) = (float4){acm[4], acm[5], acm[6], acm[7]};
}

// ================= FALLBACK (verbatim R3, measured 650us): fused BM=64 =================
#define BM 64
#define BUH 512
#define NRT 128
#define WT_BYTES ((size_t)NE * NU * ND * 2)
#define SUMS_FLOATS ((size_t)NE * NRT * 2 * 64)
#define FLG_INTS ((size_t)NE * NRT * 2)

#define LOADB(F, soff)                                   \
  {                                                      \
    const char* p_ = wtc + (soff) + vbase;               \
    F[0] = *(const f16x8*)(p_);                          \
    F[1] = *(const f16x8*)(p_ + 1 * 16 * ND * 2);        \
    F[2] = *(const f16x8*)(p_ + 2 * 16 * ND * 2);        \
    F[3] = *(const f16x8*)(p_ + 3 * 16 * ND * 2);        \
  }

#define MFMA_HALF(F, kbyte)                                                         \
  {                                                                                 \
    const f16x8 a0 = *(const f16x8*)(A_s + (ln + 0) * 2064 + g * 16 + (kbyte));     \
    const f16x8 a1 = *(const f16x8*)(A_s + (ln + 16) * 2064 + g * 16 + (kbyte));    \
    const f16x8 a2 = *(const f16x8*)(A_s + (ln + 32) * 2064 + g * 16 + (kbyte));    \
    const f16x8 a3 = *(const f16x8*)(A_s + (ln + 48) * 2064 + g * 16 + (kbyte));    \
    _Pragma("unroll") for (int n_ = 0; n_ < 4; ++n_) {                              \
      acc[0][n_] = __builtin_amdgcn_mfma_f32_16x16x32_f16(a0, F[n_], acc[0][n_], 0, 0, 0); \
      acc[1][n_] = __builtin_amdgcn_mfma_f32_16x16x32_f16(a1, F[n_], acc[1][n_], 0, 0, 0); \
      acc[2][n_] = __builtin_amdgcn_mfma_f32_16x16x32_f16(a2, F[n_], acc[2][n_], 0, 0, 0); \
      acc[3][n_] = __builtin_amdgcn_mfma_f32_16x16x32_f16(a3, F[n_], acc[3][n_], 0, 0, 0); \
    }                                                                               \
  }

__device__ __forceinline__ size_t wt_soff(int L) {
  L = (L > 511) ? 511 : L;
  return (size_t)(L >> 5) * ((size_t)NU * ND * 2) + (size_t)(L & 31) * 64;
}

__global__ __launch_bounds__(512, 2) void k_proj(const float* __restrict__ X,
                                                 const float* __restrict__ TP,
                                                 const f16* __restrict__ WT,
                                                 const float* __restrict__ BIAS,
                                                 float* __restrict__ OUT,
                                                 float* __restrict__ SUMS,
                                                 int* __restrict__ FLG) {
  __shared__ alignas(16) unsigned char lds[132096 + 4096 + 2048 + 256];
  unsigned char* A_s = lds;
  float* tp_s = (float*)(lds + 132096);
  float* reds = (float*)(lds + 132096 + 4096);
  float* sums_s = (float*)(lds + 132096 + 4096 + 2048);

  const int t = threadIdx.x;
  const int w = t >> 6;
  const int l = t & 63;
  const int g = l >> 4;
  const int ln = l & 15;
  const int bid = blockIdx.x;
  const int rt = bid >> 1;
  const int uh = bid & 1;
  const int b0 = rt * BM;
  const int c0 = uh * BUH;

#pragma unroll
  for (int i = 0; i < 32; ++i) {
    const int idx = (i * 512 + t) << 2;
    const int row = idx >> 10;
    const int col = idx & 1023;
    const float4 v = *(const float4*)(X + (size_t)(b0 + row) * ND + col);
    f16x4 h;
    h[0] = (f16)v.x; h[1] = (f16)v.y; h[2] = (f16)v.z; h[3] = (f16)v.w;
    *(f16x4*)(A_s + row * 2064 + (col << 1)) = h;
  }
  tp_s[t] = TP[(size_t)(b0 + (t >> 4)) * NE + (t & 15)];
  tp_s[512 + t] = TP[(size_t)(b0 + 32 + (t >> 4)) * NE + (t & 15)];
  __syncthreads();

  f32x4 out_acc[4][4];
#pragma unroll
  for (int m = 0; m < 4; ++m)
#pragma unroll
    for (int n = 0; n < 4; ++n) out_acc[m][n] = (f32x4){0.f, 0.f, 0.f, 0.f};

  const char* wtc = (const char*)WT;
  const unsigned vbase = ((unsigned)(c0 + w * 64 + ln) * ND + g * 8) * 2;

  f16x8 F0[4], F1[4], F2[4], F3[4];
  LOADB(F0, wt_soff(0));
  LOADB(F1, wt_soff(1));
  LOADB(F2, wt_soff(2));

  for (int e = 0; e < NE; ++e) {
    f32x4 acc[4][4];
#pragma unroll
    for (int m = 0; m < 4; ++m)
#pragma unroll
      for (int n = 0; n < 4; ++n) acc[m][n] = (f32x4){0.f, 0.f, 0.f, 0.f};

    const int Le = e * 32;
#pragma unroll 1
    for (int gi = 0; gi < 7; ++gi) {
      const int L = Le + gi * 4;
      const int kb = gi * 4 * 64;
      LOADB(F3, wt_soff(L + 3));
      MFMA_HALF(F0, kb + 0);
      LOADB(F0, wt_soff(L + 4));
      MFMA_HALF(F1, kb + 64);
      LOADB(F1, wt_soff(L + 5));
      MFMA_HALF(F2, kb + 128);
      LOADB(F2, wt_soff(L + 6));
      MFMA_HALF(F3, kb + 192);
    }
    LOADB(F3, wt_soff(Le + 31));
    MFMA_HALF(F0, 28 * 64);
    LOADB(F0, wt_soff(Le + 32));
    MFMA_HALF(F1, 29 * 64);
    LOADB(F1, wt_soff(Le + 33));
    MFMA_HALF(F2, 30 * 64);
    LOADB(F2, wt_soff(Le + 34));
    MFMA_HALF(F3, 31 * 64);

    const float* bp = BIAS + (size_t)e * NU + c0 + w * 64 + ln;
    float bv[4];
#pragma unroll
    for (int n = 0; n < 4; ++n) bv[n] = bp[n * 16];

    float rs[4][4];
#pragma unroll
    for (int m = 0; m < 4; ++m)
#pragma unroll
      for (int r = 0; r < 4; ++r) rs[m][r] = 0.f;
#pragma unroll
    for (int m = 0; m < 4; ++m)
#pragma unroll
      for (int n = 0; n < 4; ++n)
#pragma unroll
        for (int r = 0; r < 4; ++r) {
          const float p = __expf(acc[m][n][r] + bv[n]);
          acc[m][n][r] = p;
          rs[m][r] += p;
        }
#pragma unroll
    for (int m = 0; m < 4; ++m)
#pragma unroll
      for (int r = 0; r < 4; ++r) {
        float v = rs[m][r];
        v += __shfl_xor(v, 1, 64);
        v += __shfl_xor(v, 2, 64);
        v += __shfl_xor(v, 4, 64);
        v += __shfl_xor(v, 8, 64);
        rs[m][r] = v;
      }
    if (ln == 0) {
#pragma unroll
      for (int m = 0; m < 4; ++m)
#pragma unroll
        for (int r = 0; r < 4; ++r) reds[(m * 16 + g * 4 + r) * 8 + w] = rs[m][r];
    }
    __syncthreads();

    const int pairbase = (e * NRT + rt) * 2;
    float myS = 0.f;
    if (t < 64) {
      const float* rp = reds + t * 8;
      myS = ((rp[0] + rp[1]) + (rp[2] + rp[3])) + ((rp[4] + rp[5]) + (rp[6] + rp[7]));
      __hip_atomic_store(&SUMS[(size_t)(pairbase + uh) * 64 + t], myS,
                         __ATOMIC_RELAXED, __HIP_MEMORY_SCOPE_AGENT);
    }
    __syncthreads();
    if (t == 0) {
      __threadfence();
      __hip_atomic_store(&FLG[pairbase + uh], 1, __ATOMIC_RELEASE, __HIP_MEMORY_SCOPE_AGENT);
      int spin = 0;
      while (__hip_atomic_load(&FLG[pairbase + (uh ^ 1)], __ATOMIC_ACQUIRE,
                               __HIP_MEMORY_SCOPE_AGENT) == 0 &&
             spin < 400000) {
        __builtin_amdgcn_s_sleep(2);
        ++spin;
      }
    }
    __syncthreads();
    if (t < 64) {
      const float ps = __hip_atomic_load(&SUMS[(size_t)(pairbase + (uh ^ 1)) * 64 + t],
                                         __ATOMIC_RELAXED, __HIP_MEMORY_SCOPE_AGENT);
      sums_s[t] = myS + ps;
    }
    __syncthreads();

#pragma unroll
    for (int m = 0; m < 4; ++m)
#pragma unroll
      for (int r = 0; r < 4; ++r) {
        const int row = m * 16 + g * 4 + r;
        const float scale = tp_s[row * 16 + e] * __builtin_amdgcn_rcpf(sums_s[row]);
#pragma unroll
        for (int n = 0; n < 4; ++n) out_acc[m][n][r] += scale * acc[m][n][r];
      }
  }

#pragma unroll
  for (int m = 0; m < 4; ++m)
#pragma unroll
    for (int r = 0; r < 4; ++r) {
      float* op = OUT + (size_t)(b0 + m * 16 + g * 4 + r) * NU + c0 + w * 64 + ln;
#pragma unroll
      for (int n = 0; n < 4; ++n) op[n * 16] = out_acc[m][n][r];
    }
}

// ================= launch =================
extern "C" void kernel_launch(void* const* d_in, const int* in_sizes, int n_in,
                              void* d_out, int out_size, void* d_ws, size_t ws_size,
                              hipStream_t stream) {
  const float* X = (const float*)d_in[0];     // [8192,1024] f32
  const float* TP = (const float*)d_in[1];    // [8192,16,1] f32
  const float* W = (const float*)d_in[2];     // [16,1024,1024] f32
  const float* BIAS = (const float*)d_in[3];  // [16,1024] f32
  float* OUT = (float*)d_out;                 // [8192,1024] f32

  const size_t XH_BYTES = (size_t)NB * ND * 2;  // 16,777,216
  const size_t FIXED = WT_BYTES + XH_BYTES;     // 50,331,648

  int CR = 0;
  for (int cr = NB; cr >= 1024; cr >>= 1) {
    const size_t need = FIXED + (size_t)cr * 16384 * 2 + (size_t)cr * 64 * 4;
    if (ws_size >= need) { CR = cr; break; }
  }

  if (CR > 0) {
    f16* WT = (f16*)d_ws;
    f16* Xh = (f16*)((char*)d_ws + WT_BYTES);
    float* S4 = (float*)((char*)d_ws + FIXED);
    f16* P = (f16*)((char*)d_ws + FIXED + (size_t)CR * 64 * 4);

    k_prep<<<dim3(8192), dim3(256), 0, stream>>>(W, WT, X, Xh);

    const int MT = CR / 256;
    const int TPB = MT / 4;
    const int nch = NB / CR;
    for (int ch = 0; ch < nch; ++ch) {
      const int RB = ch * CR;
      k_gemm_exp<<<dim3(256), dim3(512), 0, stream>>>(
          (const f16*)((const char*)Xh + (size_t)RB * ND * 2), WT, BIAS, P, S4, TPB, CR);
      k_combine<<<dim3(CR / 4), dim3(512), 0, stream>>>(P, TP, S4, OUT, RB, CR);
    }
  } else {
    // fallback: proven fused BM=64 path (R3, 650us); W-transpose only (grid 4096)
    f16* WT = (f16*)d_ws;
    float* SUMS = (float*)((char*)d_ws + WT_BYTES);
    int* FLG = (int*)((char*)d_ws + WT_BYTES + SUMS_FLOATS * 4);

    hipMemsetAsync(FLG, 0, FLG_INTS * sizeof(int), stream);
    k_prep<<<dim3(4096), dim3(256), 0, stream>>>(W, WT, X, nullptr);
    k_proj<<<dim3(256), dim3(512), 0, stream>>>(X, TP, WT, BIAS, OUT, SUMS, FLG);
  }
}

// Round 12
// 376.431 us; speedup vs baseline: 1.2267x; 1.2267x over previous
//
#include <hip/hip_runtime.h>
#include <hip/hip_bf16.h>
#include <hip/hip_fp16.h>
#include <stdint.h>

typedef _Float16 f16;
typedef _Float16 f16x4 __attribute__((ext_vector_type(4)));
typedef _Float16 f16x8 __attribute__((ext_vector_type(8)));
typedef float f32x4 __attribute__((ext_vector_type(4)));

#define NB 8192
#define ND 1024
#define NU 1024
#define NE 16

// ---------------- merged prep: W transpose-cast + X cast, one launch ----------------
__global__ __launch_bounds__(256) void k_prep(const float* __restrict__ W,
                                              f16* __restrict__ WT,
                                              const float* __restrict__ X,
                                              f16* __restrict__ Xh) {
  const int bid = blockIdx.x;
  const int t = threadIdx.x;
  if (bid < 4096) {
    __shared__ f16 tile[64][68];
    const int u0 = (bid & 15) * 64;
    const int d0 = ((bid >> 4) & 15) * 64;
    const int e = bid >> 8;
    const int r = t >> 4;
    const int c = (t & 15) << 2;
    const float* src = W + (size_t)e * ND * NU;
    f16* dst = WT + (size_t)e * NU * ND;
#pragma unroll
    for (int i = 0; i < 4; ++i) {
      const int rr = r + i * 16;
      const float4 v = *(const float4*)(src + (size_t)(d0 + rr) * NU + (u0 + c));
      tile[rr][c + 0] = (f16)v.x;
      tile[rr][c + 1] = (f16)v.y;
      tile[rr][c + 2] = (f16)v.z;
      tile[rr][c + 3] = (f16)v.w;
    }
    __syncthreads();
#pragma unroll
    for (int i = 0; i < 4; ++i) {
      const int rr = r + i * 16;
      f16x4 h;
      h[0] = tile[c + 0][rr];
      h[1] = tile[c + 1][rr];
      h[2] = tile[c + 2][rr];
      h[3] = tile[c + 3][rr];
      *(f16x4*)(dst + (size_t)(u0 + rr) * ND + (d0 + c)) = h;
    }
  } else {
    const size_t i = ((size_t)(bid - 4096) * 256 + t) * 8;
    const float4 v0 = *(const float4*)(X + i);
    const float4 v1 = *(const float4*)(X + i + 4);
    f16x8 h;
    h[0] = (f16)v0.x; h[1] = (f16)v0.y; h[2] = (f16)v0.z; h[3] = (f16)v0.w;
    h[4] = (f16)v1.x; h[5] = (f16)v1.y; h[6] = (f16)v1.z; h[7] = (f16)v1.w;
    *(f16x8*)(Xh + i) = h;
  }
}

// ================= PHASE A: persistent 256x256 GEMM + exp epilogue =================
// R10 dataflow (A+B LDS, 4-phase, vmcnt(6)) + HOISTED ADDRESSES: K-loop unrolled x2
// so buf is compile-time; 8 loop-invariant LDS base regs, ds_read = base + imm
// (folds into offset:); stage src/dst offsets precomputed per-thread.

typedef __attribute__((address_space(3))) void lds_void_t;
typedef __attribute__((address_space(1))) const void gbl_void_t;

__device__ __forceinline__ void gload16(const void* g, void* l) {
  __builtin_amdgcn_global_load_lds((gbl_void_t*)g, (lds_void_t*)l, 16, 0, 0);
}

#define WAIT_VM6() do { asm volatile("s_waitcnt vmcnt(6)" ::: "memory"); \
                        __builtin_amdgcn_sched_barrier(0); } while (0)
#define WAIT_VM0() do { asm volatile("s_waitcnt vmcnt(0)" ::: "memory"); \
                        __builtin_amdgcn_sched_barrier(0); } while (0)
#define WAIT_LGKM0() do { asm volatile("s_waitcnt lgkmcnt(0)" ::: "memory"); \
                          __builtin_amdgcn_sched_barrier(0); } while (0)
#define BARR() do { asm volatile("" ::: "memory"); __builtin_amdgcn_s_barrier(); \
                    asm volatile("" ::: "memory"); } while (0)

// stage half h (op 0=A 1=B) at byte k-offset kb into dbuf BUF (literal)
#define STG(srcp, op, h, kb, BUF)                                               \
  { _Pragma("unroll") for (int i_ = 0; i_ < 2; ++i_)                            \
      gload16((srcp) + (h) * 262144 + (size_t)(kb) + sOff[i_],                  \
              smem + ((BUF) * 65536 + (op) * 32768 + (h) * 16384) + dOff[i_]); }

#define LDA2(mb0, CB)                                                           \
  _Pragma("unroll") for (int j_ = 0; j_ < 4; ++j_) {                            \
    a[j_][0] = *(const f16x8*)(smem + A0b[CB] + ((mb0) + j_) * 2048);           \
    a[j_][1] = *(const f16x8*)(smem + A1b[CB] + ((mb0) + j_) * 2048);           \
  }

#define LDB2(CB)                                                                \
  _Pragma("unroll") for (int n_ = 0; n_ < 4; ++n_) {                            \
    b[n_][0] = *(const f16x8*)(smem + B0b[CB] + n_ * 2048);                     \
    b[n_][1] = *(const f16x8*)(smem + B1b[CB] + n_ * 2048);                     \
  }

#define QUAD(mb0, n0)                                                           \
  _Pragma("unroll") for (int j_ = 0; j_ < 4; ++j_)                              \
    _Pragma("unroll") for (int n_ = 0; n_ < 2; ++n_)                            \
      _Pragma("unroll") for (int ks_ = 0; ks_ < 2; ++ks_)                       \
        acc[(mb0) + j_][(n0) + n_] = __builtin_amdgcn_mfma_f32_16x16x32_f16(    \
            a[j_][ks_], b[(n0) + n_][ks_], acc[(mb0) + j_][(n0) + n_], 0, 0, 0);

// one K-tile body; CB = compile-time dbuf of kt
#define KBODY(ktv, CB)                                                          \
  {                                                                             \
    const int kt_ = (ktv);                                                      \
    const bool lastT_ = ((kt_ >> 4) == TPB - 1);                                \
    const bool lastk_ = (kt_ == TOT - 1);                                       \
    const bool sk14_ = lastT_ && ((kt_ & 15) >= 14);                            \
    const int kt1_ = lastk_ ? kt_ : kt_ + 1;                                    \
    const char* Ag1_ = Xc0 + (size_t)(mt0 + (kt1_ >> 4)) * 524288;              \
    const int kb1_ = (kt1_ & 15) * 128;                                         \
    const int kt2_ = (kt_ + 2 < TOT) ? kt_ + 2 : kt_;                           \
    const char* Ag2_ = Xc0 + (size_t)(mt0 + (kt2_ >> 4)) * 524288;              \
    const int kb2_ = (kt2_ & 15) * 128;                                         \
    if (lastk_) { WAIT_VM0(); BARR(); }                                         \
    LDA2(0, CB);                                                                \
    LDB2(CB);                                                                   \
    if (!lastk_) STG(Ag1_, 0, 1, kb1_, (CB) ^ 1);                               \
    BARR();                                                                     \
    __builtin_amdgcn_s_setprio(1); QUAD(0, 0); __builtin_amdgcn_s_setprio(0);   \
    BARR();                                                                     \
    if (!sk14_) STG(Bg, 1, 0, kb2_, CB);                                        \
    BARR();                                                                     \
    __builtin_amdgcn_s_setprio(1); QUAD(0, 2); __builtin_amdgcn_s_setprio(0);   \
    BARR();                                                                     \
    LDA2(4, CB);                                                                \
    if (!sk14_) STG(Bg, 1, 1, kb2_, CB);                                        \
    BARR();                                                                     \
    __builtin_amdgcn_s_setprio(1); QUAD(4, 2); __builtin_amdgcn_s_setprio(0);   \
    BARR();                                                                     \
    if (!sk14_) STG(Ag2_, 0, 0, kb2_, CB);                                      \
    BARR();                                                                     \
    __builtin_amdgcn_s_setprio(1); QUAD(4, 0); __builtin_amdgcn_s_setprio(0);   \
    if (!lastk_) WAIT_VM6();                                                    \
    BARR();                                                                     \
  }

__global__ __launch_bounds__(512, 2) void k_gemm_exp(const f16* __restrict__ Xc,
                                                     const f16* __restrict__ WT,
                                                     const float* __restrict__ BIAS,
                                                     f16* __restrict__ P,
                                                     float* __restrict__ S4,
                                                     int TPB, int CR) {
  __shared__ alignas(16) unsigned char smem[131072 + 4096];
  float* red = (float*)(smem + 131072);

  const int t = threadIdx.x;
  const int w = t >> 6;
  const int l = t & 63;
  const int g = l >> 4;
  const int ln = l & 15;
  const int wr = w >> 2;  // 0..1
  const int wc = w & 3;   // 0..3

  const int bid = blockIdx.x;
  const int xcd = bid & 7;
  const int i = bid >> 3;
  const int ntl = i >> 2;
  const int q = i & 3;
  const int nt = xcd * 8 + ntl;
  const int mt0 = q * TPB;

  const char* Xc0 = (const char*)Xc;
  const char* Bg = (const char*)WT + (size_t)nt * 524288;

  // ---- hoisted LDS read bases (byte offsets), per dbuf ----
  const unsigned aRow = (unsigned)(wr * 128 + ln) * 128;
  const unsigned bRow = 32768u + (unsigned)(wc >> 1) * 16384 +
                        (unsigned)((wc & 1) * 64 + ln) * 128;
  const unsigned x0 = (unsigned)(g ^ (ln & 7)) * 16;
  const unsigned x1 = (unsigned)((4 + g) ^ (ln & 7)) * 16;
  const unsigned A0b[2] = {aRow + x0, aRow + x0 + 65536u};
  const unsigned A1b[2] = {aRow + x1, aRow + x1 + 65536u};
  const unsigned B0b[2] = {bRow + x0, bRow + x0 + 65536u};
  const unsigned B1b[2] = {bRow + x1, bRow + x1 + 65536u};

  // ---- hoisted stage offsets (per-thread invariant) ----
  unsigned sOff[2], dOff[2];
#pragma unroll
  for (int i_ = 0; i_ < 2; ++i_) {
    const unsigned s_ = i_ * 512 + t;
    sOff[i_] = (s_ >> 3) * 2048 + (((s_ & 7) ^ ((s_ >> 3) & 7)) * 16);
    dOff[i_] = (i_ * 512 + (t & ~63u)) * 16;
  }

  f32x4 acc[8][4];
#pragma unroll
  for (int mb = 0; mb < 8; ++mb)
#pragma unroll
    for (int nb = 0; nb < 4; ++nb) acc[mb][nb] = (f32x4){0.f, 0.f, 0.f, 0.f};

  f16x8 a[4][2], b[4][2];

  float bv[4];
  const float* bp = BIAS + ((size_t)(nt >> 2) << 10) + (nt & 3) * 256 + wc * 64 + ln;
#pragma unroll
  for (int nb = 0; nb < 4; ++nb) bv[nb] = bp[nb * 16];

  const int TOT = TPB * 16;

  // prologue: kt0 fully into buf0; kt1 all but A1 into buf1 (A1(kt1) lands in P1 of kt0)
  {
    const char* Ag0 = Xc0 + (size_t)mt0 * 524288;
    STG(Ag0, 0, 0, 0, 0);
    STG(Ag0, 0, 1, 0, 0);
    STG(Bg, 1, 0, 0, 0);
    STG(Bg, 1, 1, 0, 0);
    STG(Bg, 1, 0, 128, 1);
    STG(Bg, 1, 1, 128, 1);
    STG(Ag0, 0, 0, 128, 1);
    WAIT_VM6();
    BARR();
  }

#pragma unroll 1
  for (int kp = 0; kp < (TOT >> 1); ++kp) {
    KBODY(kp * 2, 0);
    KBODY(kp * 2 + 1, 1);

    if (((kp * 2 + 1) & 15) == 15) {
      // ---- epilogue: bias + exp + f16 P store + row-sums (raw barriers; in-flight
      // next-tile stages never drained) ----
      const int mt = mt0 + ((kp * 2 + 1) >> 4);
      f16* Prow =
          P + (size_t)(mt * 256 + wr * 128) * 16384 + (size_t)nt * 256 + wc * 64 + ln;
#pragma unroll
      for (int mb = 0; mb < 8; ++mb) {
        float rs[4] = {0.f, 0.f, 0.f, 0.f};
#pragma unroll
        for (int nb = 0; nb < 4; ++nb) {
#pragma unroll
          for (int r = 0; r < 4; ++r) {
            const float p = __expf(acc[mb][nb][r] + bv[nb]);
            rs[r] += p;
            Prow[(size_t)(mb * 16 + g * 4 + r) * 16384 + nb * 16] = (f16)p;
            acc[mb][nb][r] = 0.f;
          }
        }
#pragma unroll
        for (int r = 0; r < 4; ++r) {
          float v = rs[r];
          v += __shfl_xor(v, 1);
          v += __shfl_xor(v, 2);
          v += __shfl_xor(v, 4);
          v += __shfl_xor(v, 8);
          if (ln == 0) red[(wr * 128 + mb * 16 + g * 4 + r) * 4 + wc] = v;
        }
      }
      WAIT_LGKM0();  // red ds_writes visible before raw barrier
      BARR();
      if (t < 256) {
        const float s =
            (red[t * 4 + 0] + red[t * 4 + 1]) + (red[t * 4 + 2] + red[t * 4 + 3]);
        S4[(size_t)nt * CR + mt * 256 + t] = s;
      }
      BARR();
    }
  }
}

// ================= PHASE B: out[b,u] = sum_e (tp/S) * P[b_local,e,u] =================
__global__ __launch_bounds__(512) void k_combine(const f16* __restrict__ P,
                                                 const float* __restrict__ TP,
                                                 const float* __restrict__ S4,
                                                 float* __restrict__ OUT,
                                                 int RB, int CR) {
  __shared__ float c_s[4][16];
  const int t = threadIdx.x;
  const int blk = blockIdx.x;
  if (t < 64) {
    const int rr = t >> 4, e = t & 15;
    const int bl = blk * 4 + rr;
    float S = 0.f;
#pragma unroll
    for (int q = 0; q < 4; ++q) S += S4[(size_t)(e * 4 + q) * CR + bl];
    c_s[rr][e] = TP[(size_t)(RB + bl) * NE + e] / S;
  }
  __syncthreads();
  const int rl = t >> 7;
  const int bl = blk * 4 + rl;
  const int u0 = (t & 127) * 8;
  float acm[8] = {0.f, 0.f, 0.f, 0.f, 0.f, 0.f, 0.f, 0.f};
  const f16* Pb = P + (size_t)bl * 16384 + u0;
#pragma unroll
  for (int e = 0; e < NE; ++e) {
    const float c = c_s[rl][e];
    const f16x8 pv = *(const f16x8*)(Pb + e * 1024);
#pragma unroll
    for (int jj = 0; jj < 8; ++jj) acm[jj] += c * (float)pv[jj];
  }
  float* op = OUT + (size_t)(RB + bl) * NU + u0;
  *(float4*)(op) = (float4){acm[0], acm[1], acm[2], acm[3]};
  *(float4*)(op + 4) = (float4){acm[4], acm[5], acm[6], acm[7]};
}

// ================= FALLBACK (verbatim R3, measured 650us): fused BM=64 =================
#define BM 64
#define BUH 512
#define NRT 128
#define WT_BYTES ((size_t)NE * NU * ND * 2)
#define SUMS_FLOATS ((size_t)NE * NRT * 2 * 64)
#define FLG_INTS ((size_t)NE * NRT * 2)

#define LOADB(F, soff)                                   \
  {                                                      \
    const char* p_ = wtc + (soff) + vbase;               \
    F[0] = *(const f16x8*)(p_);                          \
    F[1] = *(const f16x8*)(p_ + 1 * 16 * ND * 2);        \
    F[2] = *(const f16x8*)(p_ + 2 * 16 * ND * 2);        \
    F[3] = *(const f16x8*)(p_ + 3 * 16 * ND * 2);        \
  }

#define MFMA_HALF(F, kbyte)                                                         \
  {                                                                                 \
    const f16x8 a0 = *(const f16x8*)(A_s + (ln + 0) * 2064 + g * 16 + (kbyte));     \
    const f16x8 a1 = *(const f16x8*)(A_s + (ln + 16) * 2064 + g * 16 + (kbyte));    \
    const f16x8 a2 = *(const f16x8*)(A_s + (ln + 32) * 2064 + g * 16 + (kbyte));    \
    const f16x8 a3 = *(const f16x8*)(A_s + (ln + 48) * 2064 + g * 16 + (kbyte));    \
    _Pragma("unroll") for (int n_ = 0; n_ < 4; ++n_) {                              \
      acc[0][n_] = __builtin_amdgcn_mfma_f32_16x16x32_f16(a0, F[n_], acc[0][n_], 0, 0, 0); \
      acc[1][n_] = __builtin_amdgcn_mfma_f32_16x16x32_f16(a1, F[n_], acc[1][n_], 0, 0, 0); \
      acc[2][n_] = __builtin_amdgcn_mfma_f32_16x16x32_f16(a2, F[n_], acc[2][n_], 0, 0, 0); \
      acc[3][n_] = __builtin_amdgcn_mfma_f32_16x16x32_f16(a3, F[n_], acc[3][n_], 0, 0, 0); \
    }                                                                               \
  }

__device__ __forceinline__ size_t wt_soff(int L) {
  L = (L > 511) ? 511 : L;
  return (size_t)(L >> 5) * ((size_t)NU * ND * 2) + (size_t)(L & 31) * 64;
}

__global__ __launch_bounds__(512, 2) void k_proj(const float* __restrict__ X,
                                                 const float* __restrict__ TP,
                                                 const f16* __restrict__ WT,
                                                 const float* __restrict__ BIAS,
                                                 float* __restrict__ OUT,
                                                 float* __restrict__ SUMS,
                                                 int* __restrict__ FLG) {
  __shared__ alignas(16) unsigned char lds[132096 + 4096 + 2048 + 256];
  unsigned char* A_s = lds;
  float* tp_s = (float*)(lds + 132096);
  float* reds = (float*)(lds + 132096 + 4096);
  float* sums_s = (float*)(lds + 132096 + 4096 + 2048);

  const int t = threadIdx.x;
  const int w = t >> 6;
  const int l = t & 63;
  const int g = l >> 4;
  const int ln = l & 15;
  const int bid = blockIdx.x;
  const int rt = bid >> 1;
  const int uh = bid & 1;
  const int b0 = rt * BM;
  const int c0 = uh * BUH;

#pragma unroll
  for (int i = 0; i < 32; ++i) {
    const int idx = (i * 512 + t) << 2;
    const int row = idx >> 10;
    const int col = idx & 1023;
    const float4 v = *(const float4*)(X + (size_t)(b0 + row) * ND + col);
    f16x4 h;
    h[0] = (f16)v.x; h[1] = (f16)v.y; h[2] = (f16)v.z; h[3] = (f16)v.w;
    *(f16x4*)(A_s + row * 2064 + (col << 1)) = h;
  }
  tp_s[t] = TP[(size_t)(b0 + (t >> 4)) * NE + (t & 15)];
  tp_s[512 + t] = TP[(size_t)(b0 + 32 + (t >> 4)) * NE + (t & 15)];
  __syncthreads();

  f32x4 out_acc[4][4];
#pragma unroll
  for (int m = 0; m < 4; ++m)
#pragma unroll
    for (int n = 0; n < 4; ++n) out_acc[m][n] = (f32x4){0.f, 0.f, 0.f, 0.f};

  const char* wtc = (const char*)WT;
  const unsigned vbase = ((unsigned)(c0 + w * 64 + ln) * ND + g * 8) * 2;

  f16x8 F0[4], F1[4], F2[4], F3[4];
  LOADB(F0, wt_soff(0));
  LOADB(F1, wt_soff(1));
  LOADB(F2, wt_soff(2));

  for (int e = 0; e < NE; ++e) {
    f32x4 acc[4][4];
#pragma unroll
    for (int m = 0; m < 4; ++m)
#pragma unroll
      for (int n = 0; n < 4; ++n) acc[m][n] = (f32x4){0.f, 0.f, 0.f, 0.f};

    const int Le = e * 32;
#pragma unroll 1
    for (int gi = 0; gi < 7; ++gi) {
      const int L = Le + gi * 4;
      const int kb = gi * 4 * 64;
      LOADB(F3, wt_soff(L + 3));
      MFMA_HALF(F0, kb + 0);
      LOADB(F0, wt_soff(L + 4));
      MFMA_HALF(F1, kb + 64);
      LOADB(F1, wt_soff(L + 5));
      MFMA_HALF(F2, kb + 128);
      LOADB(F2, wt_soff(L + 6));
      MFMA_HALF(F3, kb + 192);
    }
    LOADB(F3, wt_soff(Le + 31));
    MFMA_HALF(F0, 28 * 64);
    LOADB(F0, wt_soff(Le + 32));
    MFMA_HALF(F1, 29 * 64);
    LOADB(F1, wt_soff(Le + 33));
    MFMA_HALF(F2, 30 * 64);
    LOADB(F2, wt_soff(Le + 34));
    MFMA_HALF(F3, 31 * 64);

    const float* bp = BIAS + (size_t)e * NU + c0 + w * 64 + ln;
    float bv[4];
#pragma unroll
    for (int n = 0; n < 4; ++n) bv[n] = bp[n * 16];

    float rs[4][4];
#pragma unroll
    for (int m = 0; m < 4; ++m)
#pragma unroll
      for (int r = 0; r < 4; ++r) rs[m][r] = 0.f;
#pragma unroll
    for (int m = 0; m < 4; ++m)
#pragma unroll
      for (int n = 0; n < 4; ++n)
#pragma unroll
        for (int r = 0; r < 4; ++r) {
          const float p = __expf(acc[m][n][r] + bv[n]);
          acc[m][n][r] = p;
          rs[m][r] += p;
        }
#pragma unroll
    for (int m = 0; m < 4; ++m)
#pragma unroll
      for (int r = 0; r < 4; ++r) {
        float v = rs[m][r];
        v += __shfl_xor(v, 1, 64);
        v += __shfl_xor(v, 2, 64);
        v += __shfl_xor(v, 4, 64);
        v += __shfl_xor(v, 8, 64);
        rs[m][r] = v;
      }
    if (ln == 0) {
#pragma unroll
      for (int m = 0; m < 4; ++m)
#pragma unroll
        for (int r = 0; r < 4; ++r) reds[(m * 16 + g * 4 + r) * 8 + w] = rs[m][r];
    }
    __syncthreads();

    const int pairbase = (e * NRT + rt) * 2;
    float myS = 0.f;
    if (t < 64) {
      const float* rp = reds + t * 8;
      myS = ((rp[0] + rp[1]) + (rp[2] + rp[3])) + ((rp[4] + rp[5]) + (rp[6] + rp[7]));
      __hip_atomic_store(&SUMS[(size_t)(pairbase + uh) * 64 + t], myS,
                         __ATOMIC_RELAXED, __HIP_MEMORY_SCOPE_AGENT);
    }
    __syncthreads();
    if (t == 0) {
      __threadfence();
      __hip_atomic_store(&FLG[pairbase + uh], 1, __ATOMIC_RELEASE, __HIP_MEMORY_SCOPE_AGENT);
      int spin = 0;
      while (__hip_atomic_load(&FLG[pairbase + (uh ^ 1)], __ATOMIC_ACQUIRE,
                               __HIP_MEMORY_SCOPE_AGENT) == 0 &&
             spin < 400000) {
        __builtin_amdgcn_s_sleep(2);
        ++spin;
      }
    }
    __syncthreads();
    if (t < 64) {
      const float ps = __hip_atomic_load(&SUMS[(size_t)(pairbase + (uh ^ 1)) * 64 + t],
                                         __ATOMIC_RELAXED, __HIP_MEMORY_SCOPE_AGENT);
      sums_s[t] = myS + ps;
    }
    __syncthreads();

#pragma unroll
    for (int m = 0; m < 4; ++m)
#pragma unroll
      for (int r = 0; r < 4; ++r) {
        const int row = m * 16 + g * 4 + r;
        const float scale = tp_s[row * 16 + e] * __builtin_amdgcn_rcpf(sums_s[row]);
#pragma unroll
        for (int n = 0; n < 4; ++n) out_acc[m][n][r] += scale * acc[m][n][r];
      }
  }

#pragma unroll
  for (int m = 0; m < 4; ++m)
#pragma unroll
    for (int r = 0; r < 4; ++r) {
      float* op = OUT + (size_t)(b0 + m * 16 + g * 4 + r) * NU + c0 + w * 64 + ln;
#pragma unroll
      for (int n = 0; n < 4; ++n) op[n * 16] = out_acc[m][n][r];
    }
}

// ================= launch =================
extern "C" void kernel_launch(void* const* d_in, const int* in_sizes, int n_in,
                              void* d_out, int out_size, void* d_ws, size_t ws_size,
                              hipStream_t stream) {
  const float* X = (const float*)d_in[0];     // [8192,1024] f32
  const float* TP = (const float*)d_in[1];    // [8192,16,1] f32
  const float* W = (const float*)d_in[2];     // [16,1024,1024] f32
  const float* BIAS = (const float*)d_in[3];  // [16,1024] f32
  float* OUT = (float*)d_out;                 // [8192,1024] f32

  const size_t XH_BYTES = (size_t)NB * ND * 2;  // 16,777,216
  const size_t FIXED = WT_BYTES + XH_BYTES;     // 50,331,648

  int CR = 0;
  for (int cr = NB; cr >= 1024; cr >>= 1) {
    const size_t need = FIXED + (size_t)cr * 16384 * 2 + (size_t)cr * 64 * 4;
    if (ws_size >= need) { CR = cr; break; }
  }

  if (CR > 0) {
    f16* WT = (f16*)d_ws;
    f16* Xh = (f16*)((char*)d_ws + WT_BYTES);
    float* S4 = (float*)((char*)d_ws + FIXED);
    f16* P = (f16*)((char*)d_ws + FIXED + (size_t)CR * 64 * 4);

    k_prep<<<dim3(8192), dim3(256), 0, stream>>>(W, WT, X, Xh);

    const int MT = CR / 256;
    const int TPB = MT / 4;
    const int nch = NB / CR;
    for (int ch = 0; ch < nch; ++ch) {
      const int RB = ch * CR;
      k_gemm_exp<<<dim3(256), dim3(512), 0, stream>>>(
          (const f16*)((const char*)Xh + (size_t)RB * ND * 2), WT, BIAS, P, S4, TPB, CR);
      k_combine<<<dim3(CR / 4), dim3(512), 0, stream>>>(P, TP, S4, OUT, RB, CR);
    }
  } else {
    // fallback: proven fused BM=64 path (R3, 650us); W-transpose only (grid 4096)
    f16* WT = (f16*)d_ws;
    float* SUMS = (float*)((char*)d_ws + WT_BYTES);
    int* FLG = (int*)((char*)d_ws + WT_BYTES + SUMS_FLOATS * 4);

    hipMemsetAsync(FLG, 0, FLG_INTS * sizeof(int), stream);
    k_prep<<<dim3(4096), dim3(256), 0, stream>>>(W, WT, X, nullptr);
    k_proj<<<dim3(256), dim3(512), 0, stream>>>(X, TP, WT, BIAS, OUT, SUMS, FLG);
  }
}